// Round 1
// baseline (584.562 us; speedup 1.0000x reference)
//
#include <hip/hip_runtime.h>
#include <hip/hip_bf16.h>

typedef short short8 __attribute__((ext_vector_type(8)));
typedef float f32x4 __attribute__((ext_vector_type(4)));

#define T_ 512
#define B_ 1024
#define D_ 128
#define H_ 64
#define A_ 18
#define TB_ (T_*B_)

// ws layout (ushort units): [x_actor | x_critic | bf16 weights]
#define XELEMS (TB_*H_)          // 33554432 per branch
#define WBASE  (2*XELEMS)
#define WBR    38912             // per-branch weight elems
#define W1OFF  0
#define W2OFF  8192
#define WIHOFF 12288
#define WHHOFF 24576
#define WHDOFF 36864

// out layout (floats): logits | values | actor_state | critic_state
#define LOGN  (TB_*A_)           // 9437184
#define VOFF_ LOGN
#define SOFF_ (LOGN + TB_)       // 9961472

__device__ __forceinline__ ushort f2bf(float f) {
  __hip_bfloat16 h = __float2bfloat16(f);
  return __builtin_bit_cast(ushort, h);
}
__device__ __forceinline__ float sigm(float x) {
  float e = __builtin_amdgcn_exp2f(-1.44269504f * x);
  return __builtin_amdgcn_rcpf(1.0f + e);
}
__device__ __forceinline__ float tanh_(float x) {
  float e = __builtin_amdgcn_exp2f(-2.88539008f * x);
  return 2.0f * __builtin_amdgcn_rcpf(1.0f + e) - 1.0f;
}

__global__ __launch_bounds__(256) void prep_kernel(
    const float* aW1, const float* aW2, const float* aWih, const float* aWhh, const float* aWl,
    const float* cW1, const float* cW2, const float* cWih, const float* cWhh, const float* cWv,
    ushort* wts) {
  int idx = blockIdx.x * 256 + threadIdx.x;
  if (idx >= 2*WBR) return;
  int br = idx / WBR, off = idx % WBR;
  float v;
  if      (off < W2OFF)  v = (br ? cW1  : aW1 )[off];
  else if (off < WIHOFF) v = (br ? cW2  : aW2 )[off - W2OFF];
  else if (off < WHHOFF) v = (br ? cWih : aWih)[off - WIHOFF];
  else if (off < WHDOFF) v = (br ? cWhh : aWhh)[off - WHHOFF];
  else {
    int t = off - WHDOFF;
    if (br == 0) v = (t < A_*H_) ? aWl[t] : 0.f;
    else         v = (t < H_)    ? cWv[t] : 0.f;
  }
  wts[WBASE + idx] = f2bf(v);
}

// ---------------- phase 1: fused MLP for both branches, x -> ws (bf16, swizzled) --------
__global__ __launch_bounds__(256, 2) void mlp_kernel(
    const float* __restrict__ obs, const ushort* __restrict__ wts,
    const float* __restrict__ ab1, const float* __restrict__ ab2,
    const float* __restrict__ cb1, const float* __restrict__ cb2,
    ushort* __restrict__ xout) {
  __shared__ __align__(16) float  obs_lds[64 * D_];
  __shared__ __align__(16) ushort htmp[4][16 * H_];
  const int tid = threadIdx.x;
  const int l = tid & 63, w = tid >> 6;
  const int lr = l & 15, lg = l >> 4;
  const long r0 = (long)blockIdx.x * 64;
  const f32x4 fzero = {0.f, 0.f, 0.f, 0.f};

  // stage obs tile; data-chunk c of row stored at position c ^ (row&7)
  {
    const float* src = obs + r0 * D_;
    #pragma unroll
    for (int i = 0; i < 8; ++i) {
      int s = tid + i * 256;          // 16B slot id (2048 total)
      int row = s >> 5, p = s & 31;
      int c = p ^ (row & 7);
      float4 v = *(const float4*)(src + row * D_ + c * 4);
      *(float4*)(obs_lds + row * D_ + p * 4) = v;
    }
  }
  __syncthreads();

  #pragma unroll 1
  for (int br = 0; br < 2; ++br) {
    const ushort* wb = wts + WBASE + br * WBR;
    const float* b1 = br ? cb1 : ab1;
    const float* b2 = br ? cb2 : ab2;
    const int key = lr & 7;
    const int row_a = w * 16 + lr;

    // ---- layer 1: [16,128] @ [128,64]
    f32x4 acc[4];
    #pragma unroll
    for (int nt = 0; nt < 4; ++nt) acc[nt] = fzero;
    #pragma unroll
    for (int ks = 0; ks < 4; ++ks) {
      int c0 = ks * 8 + lg * 2;
      float4 f0 = *(const float4*)(obs_lds + row_a * D_ + (((c0    ) ^ key) << 2));
      float4 f1 = *(const float4*)(obs_lds + row_a * D_ + (((c0 + 1) ^ key) << 2));
      short8 a;
      a[0]=(short)f2bf(f0.x); a[1]=(short)f2bf(f0.y); a[2]=(short)f2bf(f0.z); a[3]=(short)f2bf(f0.w);
      a[4]=(short)f2bf(f1.x); a[5]=(short)f2bf(f1.y); a[6]=(short)f2bf(f1.z); a[7]=(short)f2bf(f1.w);
      #pragma unroll
      for (int nt = 0; nt < 4; ++nt) {
        int n = nt * 16 + lr;
        short8 b = *(const short8*)(wb + W1OFF + n * D_ + ks * 32 + lg * 8);
        acc[nt] = __builtin_amdgcn_mfma_f32_16x16x32_bf16(a, b, acc[nt], 0, 0, 0);
      }
    }
    // bias+relu -> htmp[w] (swizzled), wave-local
    #pragma unroll
    for (int nt = 0; nt < 4; ++nt) {
      int coln = nt * 16 + lr;
      float bias = b1[coln];
      #pragma unroll
      for (int j = 0; j < 4; ++j) {
        int row = lg * 4 + j;
        float v = fmaxf(acc[nt][j] + bias, 0.f);
        int idx = row * H_ + ((((coln >> 3) ^ (row & 7))) << 3) + (coln & 7);
        htmp[w][idx] = f2bf(v);
      }
    }
    // ---- layer 2: [16,64] @ [64,64]
    short8 a2[2];
    #pragma unroll
    for (int ks = 0; ks < 2; ++ks) {
      int c = ks * 4 + lg;
      a2[ks] = *(const short8*)(&htmp[w][lr * H_ + ((c ^ key) << 3)]);
    }
    f32x4 acc2[4];
    #pragma unroll
    for (int nt = 0; nt < 4; ++nt) acc2[nt] = fzero;
    #pragma unroll
    for (int ks = 0; ks < 2; ++ks) {
      #pragma unroll
      for (int nt = 0; nt < 4; ++nt) {
        int n = nt * 16 + lr;
        short8 b = *(const short8*)(wb + W2OFF + n * H_ + ks * 32 + lg * 8);
        acc2[nt] = __builtin_amdgcn_mfma_f32_16x16x32_bf16(a2[ks], b, acc2[nt], 0, 0, 0);
      }
    }
    #pragma unroll
    for (int nt = 0; nt < 4; ++nt) {
      int coln = nt * 16 + lr;
      float bias = b2[coln];
      #pragma unroll
      for (int j = 0; j < 4; ++j) {
        int row = lg * 4 + j;
        float v = fmaxf(acc2[nt][j] + bias, 0.f);
        int idx = row * H_ + ((((coln >> 3) ^ (row & 7))) << 3) + (coln & 7);
        htmp[w][idx] = f2bf(v);
      }
    }
    __syncthreads();
    // coalesced copy htmp (verbatim, swizzle embedded) -> global x
    {
      const uint4* sp = (const uint4*)htmp;
      uint4* dp = (uint4*)((char*)xout + (size_t)br * ((size_t)XELEMS * 2) + (size_t)r0 * (H_ * 2));
      dp[tid * 2]     = sp[tid * 2];
      dp[tid * 2 + 1] = sp[tid * 2 + 1];
    }
    __syncthreads();
  }
}

// ---------------- phase 2: GRU scan + heads -------------------------------------------
__global__ __launch_bounds__(256, 1) void scan_kernel(
    const ushort* __restrict__ ws,      // x at 0, weights at WBASE
    const float* __restrict__ dones,
    const float* __restrict__ astate, const float* __restrict__ cstate,
    const float* __restrict__ abih, const float* __restrict__ abhh, const float* __restrict__ abl,
    const float* __restrict__ cbih, const float* __restrict__ cbhh, const float* __restrict__ cbv,
    float* __restrict__ out) {
  __shared__ __align__(16) ushort hbuf[2][16 * H_];
  const int tid = threadIdx.x;
  const int l = tid & 63, w = tid >> 6;
  const int lr = l & 15, lg = l >> 4;
  const int br = blockIdx.x & 1;
  const int b0 = (blockIdx.x >> 1) * 16;
  const int key = lr & 7;
  const f32x4 fzero = {0.f, 0.f, 0.f, 0.f};
  const short8 s8zero = {0, 0, 0, 0, 0, 0, 0, 0};

  const ushort* wb = ws + WBASE + br * WBR;
  const ushort* xp = ws + (size_t)br * XELEMS;
  const float* bihp = br ? cbih : abih;
  const float* bhhp = br ? cbhh : abhh;
  const float* st   = br ? cstate : astate;

  // persistent weight B-fragments
  short8 ihB[3][2], hhB[3][2];
  #pragma unroll
  for (int g = 0; g < 3; ++g) {
    int n = g * 64 + w * 16 + lr;
    #pragma unroll
    for (int ks = 0; ks < 2; ++ks) {
      ihB[g][ks] = *(const short8*)(wb + WIHOFF + n * H_ + ks * 32 + lg * 8);
      hhB[g][ks] = *(const short8*)(wb + WHHOFF + n * H_ + ks * 32 + lg * 8);
    }
  }
  // head B-fragments
  short8 hdB[2] = {s8zero, s8zero};
  float hbias = 0.f;
  bool do_head = false;
  if (br == 0 && w < 2) {
    do_head = true;
    int n = w * 16 + lr;
    #pragma unroll
    for (int ks = 0; ks < 2; ++ks)
      hdB[ks] = (n < A_) ? *(const short8*)(wb + WHDOFF + n * H_ + ks * 32 + lg * 8) : s8zero;
    hbias = (n < A_) ? abl[n] : 0.f;
  } else if (br == 1 && w == 0) {
    do_head = true;
    #pragma unroll
    for (int ks = 0; ks < 2; ++ks)
      hdB[ks] = (lr == 0) ? *(const short8*)(wb + WHDOFF + ks * 32 + lg * 8) : s8zero;
    hbias = cbv[0];
  }

  float bi[3], bh[3];
  #pragma unroll
  for (int g = 0; g < 3; ++g) {
    int o = g * 64 + w * 16 + lr;
    bi[g] = bihp[o]; bh[g] = bhhp[o];
  }

  // h init (fp32 persistent regs: rows lg*4+j, col w*16+lr)
  float h_old[4];
  #pragma unroll
  for (int j = 0; j < 4; ++j)
    h_old[j] = st[(size_t)(b0 + lg * 4 + j) * H_ + w * 16 + lr];
  #pragma unroll
  for (int j = 0; j < 4; ++j) {
    int row = lg * 4 + j, coln = w * 16 + lr;
    int idx = row * H_ + ((((coln >> 3) ^ (row & 7))) << 3) + (coln & 7);
    hbuf[0][idx] = f2bf(h_old[j]);
  }

  auto loadx = [&](int t, short8* f) {
    size_t rowe = ((size_t)t * B_ + b0 + lr) * H_;
    #pragma unroll
    for (int ks = 0; ks < 2; ++ks) {
      int c = ks * 4 + lg;
      f[ks] = *(const short8*)(xp + rowe + ((c ^ key) << 3));
    }
  };
  auto loadd = [&](int t, float* dj, float& dl) {
    const float* dp = dones + (size_t)t * B_ + b0;
    #pragma unroll
    for (int j = 0; j < 4; ++j) dj[j] = dp[lg * 4 + j];
    dl = dp[lr];
  };

  short8 xA[2], xB[2], xC[2];
  float djA[4], djB[4], djC[4], dlA, dlB, dlC;
  loadx(0, xA); loadx(1, xB);
  loadd(0, djA, dlA); loadd(1, djB, dlB);

  int cur = 0;
  __syncthreads();

  for (int t = 0; t <= T_; ++t) {
    // prefetch t+2 (clamped)
    if (t < T_) {
      int tp = (t + 2 < T_) ? t + 2 : T_ - 1;
      loadx(tp, xC);
      loadd(tp, djC, dlC);
    }
    // read h_{t-1} fragments
    short8 hf[2];
    #pragma unroll
    for (int ks = 0; ks < 2; ++ks) {
      int c = ks * 4 + lg;
      hf[ks] = *(const short8*)(&hbuf[cur][lr * H_ + ((c ^ key) << 3)]);
    }
    // head for step t-1 (raw h, pre-reset)
    if (t > 0 && do_head) {
      f32x4 ha = fzero;
      ha = __builtin_amdgcn_mfma_f32_16x16x32_bf16(hf[0], hdB[0], ha, 0, 0, 0);
      ha = __builtin_amdgcn_mfma_f32_16x16x32_bf16(hf[1], hdB[1], ha, 0, 0, 0);
      if (br == 0) {
        int coln = w * 16 + lr;
        if (coln < A_) {
          #pragma unroll
          for (int j = 0; j < 4; ++j) {
            size_t off = ((size_t)(t - 1) * B_ + b0 + lg * 4 + j) * A_ + coln;
            out[off] = ha[j] + hbias;
          }
        }
      } else if (lr == 0) {
        #pragma unroll
        for (int j = 0; j < 4; ++j)
          out[VOFF_ + (size_t)(t - 1) * B_ + b0 + lg * 4 + j] = ha[j] + hbias;
      }
    }
    if (t == T_) break;

    // done-reset (dones are exactly 0.0/1.0)
    short8 hs0 = (dlA != 0.f) ? s8zero : hf[0];
    short8 hs1 = (dlA != 0.f) ? s8zero : hf[1];
    #pragma unroll
    for (int j = 0; j < 4; ++j) if (djA[j] != 0.f) h_old[j] = 0.f;

    // gi = x@Wih^T, gh = h@Whh^T (fp32 accum)
    f32x4 gi[3], gh[3];
    #pragma unroll
    for (int g = 0; g < 3; ++g) {
      f32x4 a = fzero, b = fzero;
      a = __builtin_amdgcn_mfma_f32_16x16x32_bf16(xA[0], ihB[g][0], a, 0, 0, 0);
      a = __builtin_amdgcn_mfma_f32_16x16x32_bf16(xA[1], ihB[g][1], a, 0, 0, 0);
      b = __builtin_amdgcn_mfma_f32_16x16x32_bf16(hs0,  hhB[g][0], b, 0, 0, 0);
      b = __builtin_amdgcn_mfma_f32_16x16x32_bf16(hs1,  hhB[g][1], b, 0, 0, 0);
      gi[g] = a; gh[g] = b;
    }
    // gates
    #pragma unroll
    for (int j = 0; j < 4; ++j) {
      float r = sigm(gi[0][j] + bi[0] + gh[0][j] + bh[0]);
      float z = sigm(gi[1][j] + bi[1] + gh[1][j] + bh[1]);
      float n = tanh_(gi[2][j] + bi[2] + r * (gh[2][j] + bh[2]));
      float hn = (1.f - z) * n + z * h_old[j];
      h_old[j] = hn;
    }
    // write h_t to other buffer
    int nxt = cur ^ 1;
    #pragma unroll
    for (int j = 0; j < 4; ++j) {
      int row = lg * 4 + j, coln = w * 16 + lr;
      int idx = row * H_ + ((((coln >> 3) ^ (row & 7))) << 3) + (coln & 7);
      hbuf[nxt][idx] = f2bf(h_old[j]);
    }
    // rotate prefetch rings
    xA[0] = xB[0]; xA[1] = xB[1]; xB[0] = xC[0]; xB[1] = xC[1];
    djA[0]=djB[0]; djA[1]=djB[1]; djA[2]=djB[2]; djA[3]=djB[3]; dlA = dlB;
    djB[0]=djC[0]; djB[1]=djC[1]; djB[2]=djC[2]; djB[3]=djC[3]; dlB = dlC;
    __syncthreads();
    cur = nxt;
  }

  // final states (fp32, post step 511)
  #pragma unroll
  for (int j = 0; j < 4; ++j) {
    size_t off = SOFF_ + (size_t)br * (B_ * H_) + (size_t)(b0 + lg * 4 + j) * H_ + w * 16 + lr;
    out[off] = h_old[j];
  }
}

extern "C" void kernel_launch(void* const* d_in, const int* in_sizes, int n_in,
                              void* d_out, int out_size, void* d_ws, size_t ws_size,
                              hipStream_t stream) {
  const float* obs    = (const float*)d_in[0];
  const float* dones  = (const float*)d_in[1];
  const float* astate = (const float*)d_in[2];
  const float* cstate = (const float*)d_in[3];
  const float* aW1  = (const float*)d_in[4];
  const float* ab1  = (const float*)d_in[5];
  const float* aW2  = (const float*)d_in[6];
  const float* ab2  = (const float*)d_in[7];
  const float* aWih = (const float*)d_in[8];
  const float* aWhh = (const float*)d_in[9];
  const float* abih = (const float*)d_in[10];
  const float* abhh = (const float*)d_in[11];
  const float* aWl  = (const float*)d_in[12];
  const float* abl  = (const float*)d_in[13];
  const float* cW1  = (const float*)d_in[14];
  const float* cb1  = (const float*)d_in[15];
  const float* cW2  = (const float*)d_in[16];
  const float* cb2  = (const float*)d_in[17];
  const float* cWih = (const float*)d_in[18];
  const float* cWhh = (const float*)d_in[19];
  const float* cbih = (const float*)d_in[20];
  const float* cbhh = (const float*)d_in[21];
  const float* cWv  = (const float*)d_in[22];
  const float* cbv  = (const float*)d_in[23];
  ushort* ws = (ushort*)d_ws;
  float* out = (float*)d_out;

  const size_t need = ((size_t)2 * XELEMS + 2 * WBR) * 2;
  if (ws_size < need) {
    // distinctive failure marker (ws too small) instead of corrupting memory
    hipMemsetAsync(d_out, 0x7F, 16, stream);
    return;
  }

  hipLaunchKernelGGL(prep_kernel, dim3(304), dim3(256), 0, stream,
                     aW1, aW2, aWih, aWhh, aWl, cW1, cW2, cWih, cWhh, cWv, ws);
  hipLaunchKernelGGL(mlp_kernel, dim3(TB_ / 64), dim3(256), 0, stream,
                     obs, ws, ab1, ab2, cb1, cb2, ws);
  hipLaunchKernelGGL(scan_kernel, dim3(128), dim3(256), 0, stream,
                     ws, dones, astate, cstate, abih, abhh, abl, cbih, cbhh, cbv, out);
}

// Round 2
// 539.792 us; speedup vs baseline: 1.0829x; 1.0829x over previous
//
#include <hip/hip_runtime.h>
#include <hip/hip_bf16.h>

typedef short short8 __attribute__((ext_vector_type(8)));
typedef float f32x4 __attribute__((ext_vector_type(4)));

#define T_ 512
#define B_ 1024
#define D_ 128
#define H_ 64
#define A_ 18
#define TB_ (T_*B_)

// ws layout (ushort units): [x_actor | x_critic | bf16 weights]
#define XELEMS (TB_*H_)          // 33554432 per branch
#define WBASE  (2*XELEMS)
#define WBR    38912             // per-branch weight elems
#define W1OFF  0
#define W2OFF  8192
#define WIHOFF 12288
#define WHHOFF 24576
#define WHDOFF 36864

// out layout (floats): logits | values | actor_state | critic_state
#define LOGN  (TB_*A_)           // 9437184
#define VOFF_ LOGN
#define SOFF_ (LOGN + TB_)       // 9961472

__device__ __forceinline__ ushort f2bf(float f) {
  __hip_bfloat16 h = __float2bfloat16(f);
  return __builtin_bit_cast(ushort, h);
}
__device__ __forceinline__ float sigm(float x) {
  float e = __builtin_amdgcn_exp2f(-1.44269504f * x);
  return __builtin_amdgcn_rcpf(1.0f + e);
}
__device__ __forceinline__ float tanh_(float x) {
  float e = __builtin_amdgcn_exp2f(-2.88539008f * x);
  return 2.0f * __builtin_amdgcn_rcpf(1.0f + e) - 1.0f;
}

__global__ __launch_bounds__(256) void prep_kernel(
    const float* aW1, const float* aW2, const float* aWih, const float* aWhh, const float* aWl,
    const float* cW1, const float* cW2, const float* cWih, const float* cWhh, const float* cWv,
    ushort* wts) {
  int idx = blockIdx.x * 256 + threadIdx.x;
  if (idx >= 2*WBR) return;
  int br = idx / WBR, off = idx % WBR;
  float v;
  if      (off < W2OFF)  v = (br ? cW1  : aW1 )[off];
  else if (off < WIHOFF) v = (br ? cW2  : aW2 )[off - W2OFF];
  else if (off < WHHOFF) v = (br ? cWih : aWih)[off - WIHOFF];
  else if (off < WHDOFF) v = (br ? cWhh : aWhh)[off - WHHOFF];
  else {
    int t = off - WHDOFF;
    if (br == 0) v = (t < A_*H_) ? aWl[t] : 0.f;
    else         v = (t < H_)    ? cWv[t] : 0.f;
  }
  wts[WBASE + idx] = f2bf(v);
}

// ---------------- phase 1: fused MLP, barrier-free, x -> ws (bf16, swizzled) ----------
__global__ __launch_bounds__(256) void mlp_kernel(
    const float* __restrict__ obs, const ushort* __restrict__ wts,
    const float* __restrict__ ab1, const float* __restrict__ ab2,
    const float* __restrict__ cb1, const float* __restrict__ cb2,
    ushort* __restrict__ xout) {
  __shared__ __align__(16) ushort htmp[4][16 * H_];   // per-wave 2KB, wave-local only
  const int tid = threadIdx.x;
  const int l = tid & 63, w = tid >> 6;
  const int lr = l & 15, lg = l >> 4;
  const int key = lr & 7;
  const long r0 = (long)blockIdx.x * 64;
  const long row = r0 + w * 16 + lr;
  const f32x4 fzero = {0.f, 0.f, 0.f, 0.f};

  // A-fragments of obs for this lane's 16-row slice (reused by both branches)
  short8 af[4];
  {
    const float* op = obs + row * D_;
    #pragma unroll
    for (int ks = 0; ks < 4; ++ks) {
      float4 f0 = *(const float4*)(op + ks * 32 + lg * 8);
      float4 f1 = *(const float4*)(op + ks * 32 + lg * 8 + 4);
      short8 a;
      a[0]=(short)f2bf(f0.x); a[1]=(short)f2bf(f0.y); a[2]=(short)f2bf(f0.z); a[3]=(short)f2bf(f0.w);
      a[4]=(short)f2bf(f1.x); a[5]=(short)f2bf(f1.y); a[6]=(short)f2bf(f1.z); a[7]=(short)f2bf(f1.w);
      af[ks] = a;
    }
  }

  #pragma unroll 1
  for (int br = 0; br < 2; ++br) {
    const ushort* wb = wts + WBASE + br * WBR;
    const float* b1 = br ? cb1 : ab1;
    const float* b2 = br ? cb2 : ab2;

    // ---- layer 1: [16,128] @ [128,64]
    f32x4 acc[4];
    #pragma unroll
    for (int nt = 0; nt < 4; ++nt) acc[nt] = fzero;
    #pragma unroll
    for (int ks = 0; ks < 4; ++ks) {
      #pragma unroll
      for (int nt = 0; nt < 4; ++nt) {
        int n = nt * 16 + lr;
        short8 b = *(const short8*)(wb + W1OFF + n * D_ + ks * 32 + lg * 8);
        acc[nt] = __builtin_amdgcn_mfma_f32_16x16x32_bf16(af[ks], b, acc[nt], 0, 0, 0);
      }
    }
    // bias+relu -> htmp[w] (swizzled), wave-local
    #pragma unroll
    for (int nt = 0; nt < 4; ++nt) {
      int coln = nt * 16 + lr;
      float bias = b1[coln];
      #pragma unroll
      for (int j = 0; j < 4; ++j) {
        int rw = lg * 4 + j;
        float v = fmaxf(acc[nt][j] + bias, 0.f);
        int idx = rw * H_ + ((((coln >> 3) ^ (rw & 7))) << 3) + (coln & 7);
        htmp[w][idx] = f2bf(v);
      }
    }
    // ---- layer 2: [16,64] @ [64,64]  (wave-local ds round-trip, no barrier)
    short8 a2[2];
    #pragma unroll
    for (int ks = 0; ks < 2; ++ks) {
      int c = ks * 4 + lg;
      a2[ks] = *(const short8*)(&htmp[w][lr * H_ + ((c ^ key) << 3)]);
    }
    f32x4 acc2[4];
    #pragma unroll
    for (int nt = 0; nt < 4; ++nt) acc2[nt] = fzero;
    #pragma unroll
    for (int ks = 0; ks < 2; ++ks) {
      #pragma unroll
      for (int nt = 0; nt < 4; ++nt) {
        int n = nt * 16 + lr;
        short8 b = *(const short8*)(wb + W2OFF + n * H_ + ks * 32 + lg * 8);
        acc2[nt] = __builtin_amdgcn_mfma_f32_16x16x32_bf16(a2[ks], b, acc2[nt], 0, 0, 0);
      }
    }
    #pragma unroll
    for (int nt = 0; nt < 4; ++nt) {
      int coln = nt * 16 + lr;
      float bias = b2[coln];
      #pragma unroll
      for (int j = 0; j < 4; ++j) {
        int rw = lg * 4 + j;
        float v = fmaxf(acc2[nt][j] + bias, 0.f);
        int idx = rw * H_ + ((((coln >> 3) ^ (rw & 7))) << 3) + (coln & 7);
        htmp[w][idx] = f2bf(v);
      }
    }
    // coalesced copy of this wave's 2KB slice (swizzle embedded) -> global x
    {
      const uint4* sp = (const uint4*)(&htmp[w][0]);
      uint4* dp = (uint4*)(xout + (size_t)br * XELEMS + (size_t)(r0 + w * 16) * H_);
      dp[l * 2]     = sp[l * 2];
      dp[l * 2 + 1] = sp[l * 2 + 1];
    }
  }
}

// ---------------- phase 2: GRU scan + heads -------------------------------------------
__global__ __launch_bounds__(256, 1) void scan_kernel(
    const ushort* __restrict__ ws,      // x at 0, weights at WBASE
    const float* __restrict__ dones,
    const float* __restrict__ astate, const float* __restrict__ cstate,
    const float* __restrict__ abih, const float* __restrict__ abhh, const float* __restrict__ abl,
    const float* __restrict__ cbih, const float* __restrict__ cbhh, const float* __restrict__ cbv,
    float* __restrict__ out) {
  __shared__ __align__(16) ushort hbuf[2][16 * H_];
  __shared__ __align__(16) float  dlds[T_ * 16];     // all dones for this slice (32KB)
  const int tid = threadIdx.x;
  const int l = tid & 63, w = tid >> 6;
  const int lr = l & 15, lg = l >> 4;
  const int br = blockIdx.x & 1;
  const int b0 = (blockIdx.x >> 1) * 16;
  const int key = lr & 7;
  const f32x4 fzero = {0.f, 0.f, 0.f, 0.f};
  const short8 s8zero = {0, 0, 0, 0, 0, 0, 0, 0};

  const ushort* wb = ws + WBASE + br * WBR;
  const ushort* xp = ws + (size_t)br * XELEMS;
  const float* bihp = br ? cbih : abih;
  const float* bhhp = br ? cbhh : abhh;
  const float* st   = br ? cstate : astate;

  // dones -> LDS (one-time)
  #pragma unroll
  for (int i = 0; i < 8; ++i) {
    int s = tid + i * 256;              // 2048 float4 slots
    int t = s >> 2, p = s & 3;
    *(float4*)(dlds + t * 16 + p * 4) = *(const float4*)(dones + (size_t)t * B_ + b0 + p * 4);
  }

  // persistent weight B-fragments
  short8 ihB[3][2], hhB[3][2];
  #pragma unroll
  for (int g = 0; g < 3; ++g) {
    int n = g * 64 + w * 16 + lr;
    #pragma unroll
    for (int ks = 0; ks < 2; ++ks) {
      ihB[g][ks] = *(const short8*)(wb + WIHOFF + n * H_ + ks * 32 + lg * 8);
      hhB[g][ks] = *(const short8*)(wb + WHHOFF + n * H_ + ks * 32 + lg * 8);
    }
  }
  // head B-fragments
  short8 hdB[2] = {s8zero, s8zero};
  float hbias = 0.f;
  bool do_head = false;
  if (br == 0 && w < 2) {
    do_head = true;
    int n = w * 16 + lr;
    #pragma unroll
    for (int ks = 0; ks < 2; ++ks)
      hdB[ks] = (n < A_) ? *(const short8*)(wb + WHDOFF + n * H_ + ks * 32 + lg * 8) : s8zero;
    hbias = (n < A_) ? abl[n] : 0.f;
  } else if (br == 1 && w == 0) {
    do_head = true;
    #pragma unroll
    for (int ks = 0; ks < 2; ++ks)
      hdB[ks] = (lr == 0) ? *(const short8*)(wb + WHDOFF + ks * 32 + lg * 8) : s8zero;
    hbias = cbv[0];
  }

  float bs0, bs1, bin, bhn;
  {
    int o0 = w * 16 + lr;
    bs0 = bihp[o0] + bhhp[o0];
    bs1 = bihp[64 + o0] + bhhp[64 + o0];
    bin = bihp[128 + o0];
    bhn = bhhp[128 + o0];
  }

  // h init (fp32 persistent regs: rows lg*4+j, col w*16+lr)
  float h_old[4];
  #pragma unroll
  for (int j = 0; j < 4; ++j)
    h_old[j] = st[(size_t)(b0 + lg * 4 + j) * H_ + w * 16 + lr];
  #pragma unroll
  for (int j = 0; j < 4; ++j) {
    int rw = lg * 4 + j, coln = w * 16 + lr;
    int idx = rw * H_ + ((((coln >> 3) ^ (rw & 7))) << 3) + (coln & 7);
    hbuf[0][idx] = f2bf(h_old[j]);
  }

  __syncthreads();   // one full barrier: dlds + hbuf[0] visible

  auto loadx = [&](int t, short8 (&f)[2]) {
    size_t rowe = ((size_t)t * B_ + b0 + lr) * H_;
    #pragma unroll
    for (int ks = 0; ks < 2; ++ks) {
      int c = ks * 4 + lg;
      f[ks] = *(const short8*)(xp + rowe + ((c ^ key) << 3));
    }
  };

  short8 bufA[2], bufB[2];
  loadx(0, bufA); loadx(1, bufB);

  int cur = 0;

  auto dostep = [&](int t, short8 (&xb)[2]) {
    // h_{t-1} fragments from LDS
    short8 hf0 = *(const short8*)(&hbuf[cur][lr * H_ + (((0 + lg) ^ key) << 3)]);
    short8 hf1 = *(const short8*)(&hbuf[cur][lr * H_ + (((4 + lg) ^ key) << 3)]);
    // dones for t (LDS)
    float dl = dlds[t * 16 + lr];
    float dj0 = dlds[t * 16 + lg * 4 + 0];
    float dj1 = dlds[t * 16 + lg * 4 + 1];
    float dj2 = dlds[t * 16 + lg * 4 + 2];
    float dj3 = dlds[t * 16 + lg * 4 + 3];

    // head for step t-1 (raw h, pre-reset)
    if (t > 0 && do_head) {
      f32x4 ha = fzero;
      ha = __builtin_amdgcn_mfma_f32_16x16x32_bf16(hf0, hdB[0], ha, 0, 0, 0);
      ha = __builtin_amdgcn_mfma_f32_16x16x32_bf16(hf1, hdB[1], ha, 0, 0, 0);
      if (br == 0) {
        int coln = w * 16 + lr;
        if (coln < A_) {
          #pragma unroll
          for (int j = 0; j < 4; ++j) {
            size_t off = ((size_t)(t - 1) * B_ + b0 + lg * 4 + j) * A_ + coln;
            out[off] = ha[j] + hbias;
          }
        }
      } else if (lr == 0) {
        #pragma unroll
        for (int j = 0; j < 4; ++j)
          out[VOFF_ + (size_t)(t - 1) * B_ + b0 + lg * 4 + j] = ha[j] + hbias;
      }
    }

    // done-reset (dones are exactly 0.0/1.0)
    short8 hs0 = (dl != 0.f) ? s8zero : hf0;
    short8 hs1 = (dl != 0.f) ? s8zero : hf1;
    float ho0 = (dj0 != 0.f) ? 0.f : h_old[0];
    float ho1 = (dj1 != 0.f) ? 0.f : h_old[1];
    float ho2 = (dj2 != 0.f) ? 0.f : h_old[2];
    float ho3 = (dj3 != 0.f) ? 0.f : h_old[3];

    // gi = x@Wih^T, gh = h@Whh^T
    f32x4 gi0 = fzero, gi1 = fzero, gi2 = fzero, gh0 = fzero, gh1 = fzero, gh2 = fzero;
    gi0 = __builtin_amdgcn_mfma_f32_16x16x32_bf16(xb[0], ihB[0][0], gi0, 0, 0, 0);
    gi0 = __builtin_amdgcn_mfma_f32_16x16x32_bf16(xb[1], ihB[0][1], gi0, 0, 0, 0);
    gi1 = __builtin_amdgcn_mfma_f32_16x16x32_bf16(xb[0], ihB[1][0], gi1, 0, 0, 0);
    gi1 = __builtin_amdgcn_mfma_f32_16x16x32_bf16(xb[1], ihB[1][1], gi1, 0, 0, 0);
    gi2 = __builtin_amdgcn_mfma_f32_16x16x32_bf16(xb[0], ihB[2][0], gi2, 0, 0, 0);
    gi2 = __builtin_amdgcn_mfma_f32_16x16x32_bf16(xb[1], ihB[2][1], gi2, 0, 0, 0);
    gh0 = __builtin_amdgcn_mfma_f32_16x16x32_bf16(hs0, hhB[0][0], gh0, 0, 0, 0);
    gh0 = __builtin_amdgcn_mfma_f32_16x16x32_bf16(hs1, hhB[0][1], gh0, 0, 0, 0);
    gh1 = __builtin_amdgcn_mfma_f32_16x16x32_bf16(hs0, hhB[1][0], gh1, 0, 0, 0);
    gh1 = __builtin_amdgcn_mfma_f32_16x16x32_bf16(hs1, hhB[1][1], gh1, 0, 0, 0);
    gh2 = __builtin_amdgcn_mfma_f32_16x16x32_bf16(hs0, hhB[2][0], gh2, 0, 0, 0);
    gh2 = __builtin_amdgcn_mfma_f32_16x16x32_bf16(hs1, hhB[2][1], gh2, 0, 0, 0);

    // prefetch t+2 into the buffer just consumed (stays in flight across barriers)
    int tp = (t + 2 < T_) ? t + 2 : T_ - 1;
    loadx(tp, xb);

    // gates
    float hn0, hn1, hn2, hn3;
    {
      float r, z, n;
      r = sigm(gi0[0] + gh0[0] + bs0); z = sigm(gi1[0] + gh1[0] + bs1);
      n = tanh_(gi2[0] + bin + r * (gh2[0] + bhn)); hn0 = (1.f - z) * n + z * ho0;
      r = sigm(gi0[1] + gh0[1] + bs0); z = sigm(gi1[1] + gh1[1] + bs1);
      n = tanh_(gi2[1] + bin + r * (gh2[1] + bhn)); hn1 = (1.f - z) * n + z * ho1;
      r = sigm(gi0[2] + gh0[2] + bs0); z = sigm(gi1[2] + gh1[2] + bs1);
      n = tanh_(gi2[2] + bin + r * (gh2[2] + bhn)); hn2 = (1.f - z) * n + z * ho2;
      r = sigm(gi0[3] + gh0[3] + bs0); z = sigm(gi1[3] + gh1[3] + bs1);
      n = tanh_(gi2[3] + bin + r * (gh2[3] + bhn)); hn3 = (1.f - z) * n + z * ho3;
    }
    h_old[0] = hn0; h_old[1] = hn1; h_old[2] = hn2; h_old[3] = hn3;

    // write h_t to other buffer
    int nxt = cur ^ 1;
    #pragma unroll
    for (int j = 0; j < 4; ++j) {
      int rw = lg * 4 + j, coln = w * 16 + lr;
      int idx = rw * H_ + ((((coln >> 3) ^ (rw & 7))) << 3) + (coln & 7);
      hbuf[nxt][idx] = f2bf(h_old[j]);
    }
    // LDS visibility only — keep x prefetch (vmcnt) in flight across the barrier
    asm volatile("s_waitcnt lgkmcnt(0)" ::: "memory");
    __builtin_amdgcn_s_barrier();
    cur = nxt;
  };

  for (int it = 0; it < T_ / 2; ++it) {
    dostep(2 * it,     bufA);
    dostep(2 * it + 1, bufB);
  }

  // epilogue: head for t = T-1 from final h in hbuf[cur]
  if (do_head) {
    short8 hf0 = *(const short8*)(&hbuf[cur][lr * H_ + (((0 + lg) ^ key) << 3)]);
    short8 hf1 = *(const short8*)(&hbuf[cur][lr * H_ + (((4 + lg) ^ key) << 3)]);
    f32x4 ha = fzero;
    ha = __builtin_amdgcn_mfma_f32_16x16x32_bf16(hf0, hdB[0], ha, 0, 0, 0);
    ha = __builtin_amdgcn_mfma_f32_16x16x32_bf16(hf1, hdB[1], ha, 0, 0, 0);
    if (br == 0) {
      int coln = w * 16 + lr;
      if (coln < A_) {
        #pragma unroll
        for (int j = 0; j < 4; ++j) {
          size_t off = ((size_t)(T_ - 1) * B_ + b0 + lg * 4 + j) * A_ + coln;
          out[off] = ha[j] + hbias;
        }
      }
    } else if (lr == 0) {
      #pragma unroll
      for (int j = 0; j < 4; ++j)
        out[VOFF_ + (size_t)(T_ - 1) * B_ + b0 + lg * 4 + j] = ha[j] + hbias;
    }
  }

  // final states (fp32, post step 511)
  #pragma unroll
  for (int j = 0; j < 4; ++j) {
    size_t off = SOFF_ + (size_t)br * (B_ * H_) + (size_t)(b0 + lg * 4 + j) * H_ + w * 16 + lr;
    out[off] = h_old[j];
  }
}

extern "C" void kernel_launch(void* const* d_in, const int* in_sizes, int n_in,
                              void* d_out, int out_size, void* d_ws, size_t ws_size,
                              hipStream_t stream) {
  const float* obs    = (const float*)d_in[0];
  const float* dones  = (const float*)d_in[1];
  const float* astate = (const float*)d_in[2];
  const float* cstate = (const float*)d_in[3];
  const float* aW1  = (const float*)d_in[4];
  const float* ab1  = (const float*)d_in[5];
  const float* aW2  = (const float*)d_in[6];
  const float* ab2  = (const float*)d_in[7];
  const float* aWih = (const float*)d_in[8];
  const float* aWhh = (const float*)d_in[9];
  const float* abih = (const float*)d_in[10];
  const float* abhh = (const float*)d_in[11];
  const float* aWl  = (const float*)d_in[12];
  const float* abl  = (const float*)d_in[13];
  const float* cW1  = (const float*)d_in[14];
  const float* cb1  = (const float*)d_in[15];
  const float* cW2  = (const float*)d_in[16];
  const float* cb2  = (const float*)d_in[17];
  const float* cWih = (const float*)d_in[18];
  const float* cWhh = (const float*)d_in[19];
  const float* cbih = (const float*)d_in[20];
  const float* cbhh = (const float*)d_in[21];
  const float* cWv  = (const float*)d_in[22];
  const float* cbv  = (const float*)d_in[23];
  ushort* ws = (ushort*)d_ws;
  float* out = (float*)d_out;

  const size_t need = ((size_t)2 * XELEMS + 2 * WBR) * 2;
  if (ws_size < need) {
    hipMemsetAsync(d_out, 0x7F, 16, stream);
    return;
  }

  hipLaunchKernelGGL(prep_kernel, dim3(304), dim3(256), 0, stream,
                     aW1, aW2, aWih, aWhh, aWl, cW1, cW2, cWih, cWhh, cWv, ws);
  hipLaunchKernelGGL(mlp_kernel, dim3(TB_ / 64), dim3(256), 0, stream,
                     obs, ws, ab1, ab2, cb1, cb2, ws);
  hipLaunchKernelGGL(scan_kernel, dim3(128), dim3(256), 0, stream,
                     ws, dones, astate, cstate, abih, abhh, abl, cbih, cbhh, cbv, out);
}